// Round 9
// baseline (346.454 us; speedup 1.0000x reference)
//
#include <hip/hip_runtime.h>

#define USH unsigned short

using s8v = __attribute__((ext_vector_type(8))) short;   // 8 x bf16 (4 VGPR)
using f4v = __attribute__((ext_vector_type(4))) float;   // MFMA accumulator

#define MFMA16(a,b,c) __builtin_amdgcn_mfma_f32_16x16x32_bf16(a,b,c,0,0,0)

// dims: B=4, F=T=1024, C=1024, H=16, D=64

__device__ __forceinline__ USH f2bf(float f) {            // RNE f32->bf16
  unsigned int u = __builtin_bit_cast(unsigned int, f);
  u += 0x7fffu + ((u >> 16) & 1u);
  return (USH)(u >> 16);
}
__device__ __forceinline__ void gload16(const void* g, void* l) {
  __builtin_amdgcn_global_load_lds((const __attribute__((address_space(1))) void*)g,
                                   (__attribute__((address_space(3))) void*)l, 16, 0, 0);
}

// ---------------- conversion kernels ----------------
__global__ __launch_bounds__(256) void cvt_qkv_k(
    const float* __restrict__ q, const float* __restrict__ k, const float* __restrict__ v,
    USH* __restrict__ oq, USH* __restrict__ ok, USH* __restrict__ ov) {
  const int which = blockIdx.y;
  const float* in = which == 0 ? q : (which == 1 ? k : v);
  USH* out = which == 0 ? oq : (which == 1 ? ok : ov);
  const int i = blockIdx.x * 256 + threadIdx.x;           // n4 = 1<<20
  float4 val = ((const float4*)in)[i];
  ushort4 o; o.x = f2bf(val.x); o.y = f2bf(val.y); o.z = f2bf(val.z); o.w = f2bf(val.w);
  ((ushort4*)out)[i] = o;
}

__global__ __launch_bounds__(256) void cvt_w_k(
    const float* __restrict__ a, const float* __restrict__ b,
    const float* __restrict__ c, const float* __restrict__ d,
    USH* __restrict__ oa, USH* __restrict__ ob, USH* __restrict__ oc, USH* __restrict__ od) {
  const int which = blockIdx.y;
  const float* in = which == 0 ? a : which == 1 ? b : which == 2 ? c : d;
  USH* out = which == 0 ? oa : which == 1 ? ob : which == 2 ? oc : od;
  const int i = blockIdx.x * 256 + threadIdx.x;           // n4 = 262144
  float4 val = ((const float4*)in)[i];
  ushort4 o; o.x = f2bf(val.x); o.y = f2bf(val.y); o.z = f2bf(val.z); o.w = f2bf(val.w);
  ((ushort4*)out)[i] = o;
}

// ---------------- GEMM core: 128x128 tile, BK=32, K=1024, B^T layout ----------------
__device__ __forceinline__ void gemm_mainloop(
    const USH* __restrict__ A, const USH* __restrict__ W,
    int rowA0, int colW0, USH* As, USH* Bs, f4v acc[4][4], int tid) {
  const int lane = tid & 63;
  const int wid = tid >> 6;
  const int l15 = lane & 15, lg = lane >> 4;
  const int wr = (wid >> 1) * 64, wc = (wid & 1) * 64;
  for (int kk = 0; kk < 32; ++kk) {
    const int k0 = kk * 32;
    {                                                     // stage 8KB A + 8KB W
      const int c0 = tid, c1 = 256 + tid;
      gload16(A + (rowA0 + (c0 >> 2)) * 1024 + k0 + (c0 & 3) * 8, As + c0 * 8);
      gload16(A + (rowA0 + (c1 >> 2)) * 1024 + k0 + (c1 & 3) * 8, As + c1 * 8);
      gload16(W + (colW0 + (c0 >> 2)) * 1024 + k0 + (c0 & 3) * 8, Bs + c0 * 8);
      gload16(W + (colW0 + (c1 >> 2)) * 1024 + k0 + (c1 & 3) * 8, Bs + c1 * 8);
    }
    __syncthreads();
    s8v a[4], b[4];
    const USH* ap = As + (wr + l15) * 32 + lg * 8;
    const USH* bp = Bs + (wc + l15) * 32 + lg * 8;
#pragma unroll
    for (int m = 0; m < 4; ++m) a[m] = *(const s8v*)(ap + m * 512);
#pragma unroll
    for (int n = 0; n < 4; ++n) b[n] = *(const s8v*)(bp + n * 512);
#pragma unroll
    for (int m = 0; m < 4; ++m)
#pragma unroll
      for (int n = 0; n < 4; ++n)
        acc[m][n] = MFMA16(a[m], b[n], acc[m][n]);
    __syncthreads();
  }
}

// fused Q/K/V projection; z selects which. Q/K -> [B,H,S,64]; V -> [B,H,64,T] (transposed)
__global__ __launch_bounds__(256) void proj_gemm_k(
    const USH* __restrict__ qb, const USH* __restrict__ kb, const USH* __restrict__ vb,
    const USH* __restrict__ Wq, const USH* __restrict__ Wk, const USH* __restrict__ Wv,
    const float* __restrict__ bq, const float* __restrict__ bk, const float* __restrict__ bv,
    USH* __restrict__ qh, USH* __restrict__ kh, USH* __restrict__ vT) {
  __shared__ USH As[128 * 32];
  __shared__ USH Bs[128 * 32];
  const int z = blockIdx.z;
  const USH* A = z == 0 ? qb : (z == 1 ? kb : vb);
  const USH* W = z == 0 ? Wq : (z == 1 ? Wk : Wv);
  const float* bias = z == 0 ? bq : (z == 1 ? bk : bv);
  f4v acc[4][4];
#pragma unroll
  for (int m = 0; m < 4; ++m)
#pragma unroll
    for (int n = 0; n < 4; ++n) acc[m][n] = f4v{0.f, 0.f, 0.f, 0.f};
  gemm_mainloop(A, W, blockIdx.y * 128, blockIdx.x * 128, As, Bs, acc, threadIdx.x);
  const int lane = threadIdx.x & 63, wid = threadIdx.x >> 6;
  const int l15 = lane & 15, lg = lane >> 4;
  const int row0 = blockIdx.y * 128 + (wid >> 1) * 64 + lg * 4;
  const int col0 = blockIdx.x * 128 + (wid & 1) * 64 + l15;
  USH* qk_dst = (z == 0) ? qh : kh;
#pragma unroll
  for (int n = 0; n < 4; ++n) {
    const int co = col0 + n * 16;
    const float bsv = bias[co];
    const int hh = co >> 6, d = co & 63;
#pragma unroll
    for (int m = 0; m < 4; ++m)
#pragma unroll
      for (int j = 0; j < 4; ++j) {
        const int rr = row0 + m * 16 + j;
        const float v = acc[m][n][j] + bsv;
        const int bb = rr >> 10, s = rr & 1023;
        if (z < 2) qk_dst[((bb * 16 + hh) << 16) + (s << 6) + d] = f2bf(v);
        else       vT[((bb * 16 + hh) << 16) + (d << 10) + s] = f2bf(v);
      }
  }
}

// output projection: d_out = ctx @ Wo^T + bo  (f32 out)
__global__ __launch_bounds__(256) void out_gemm_k(
    const USH* __restrict__ ctx, const USH* __restrict__ Wo,
    const float* __restrict__ bo, float* __restrict__ out) {
  __shared__ USH As[128 * 32];
  __shared__ USH Bs[128 * 32];
  f4v acc[4][4];
#pragma unroll
  for (int m = 0; m < 4; ++m)
#pragma unroll
    for (int n = 0; n < 4; ++n) acc[m][n] = f4v{0.f, 0.f, 0.f, 0.f};
  gemm_mainloop(ctx, Wo, blockIdx.y * 128, blockIdx.x * 128, As, Bs, acc, threadIdx.x);
  const int lane = threadIdx.x & 63, wid = threadIdx.x >> 6;
  const int l15 = lane & 15, lg = lane >> 4;
  const int row0 = blockIdx.y * 128 + (wid >> 1) * 64 + lg * 4;
  const int col0 = blockIdx.x * 128 + (wid & 1) * 64 + l15;
#pragma unroll
  for (int n = 0; n < 4; ++n) {
    const int co = col0 + n * 16;
    const float bsv = bo[co];
#pragma unroll
    for (int m = 0; m < 4; ++m)
#pragma unroll
      for (int j = 0; j < 4; ++j) {
        const int rr = row0 + m * 16 + j;
        out[rr * 1024 + co] = acc[m][n][j] + bsv;
      }
  }
}

// ---------------- flash attention (R7 structure), ABLATION-templated ----------------
// ABL=0 full; ABL=1 no K/V staging+barriers; ABL=2 no bias/mask loads; ABL=3 no softmax.
template<int ABL>
__global__ __launch_bounds__(256) void attn_abl_k(
    const USH* __restrict__ qh, const USH* __restrict__ kh, const USH* __restrict__ vT,
    const float* __restrict__ rb, const int* __restrict__ mask, USH* __restrict__ ctx) {
  __shared__ USH Ks[64 * 64];           // [t][d], col8 XOR-swizzled by (t&7)
  __shared__ USH Vs[64 * 64];           // [d][t], col8 XOR-swizzled by (d&7)
  __shared__ USH Ps[4 * 16 * 72];       // per-wave P[f][t], pad 72

  const int tid = threadIdx.x, lane = tid & 63, w = tid >> 6;
  const int l15 = lane & 15, lg = lane >> 4;
  const int swz = ((blockIdx.x & 7) << 7) | (blockIdx.x >> 3);
  const int fb = swz & 15, h = (swz >> 4) & 15, b = swz >> 8;
  const int bh = b * 16 + h;

  const int f_row = fb * 64 + w * 16 + l15;
  const USH* qptr = qh + (bh << 16) + f_row * 64 + lg * 8;
  const s8v bq0 = *(const s8v*)qptr;
  const s8v bq1 = *(const s8v*)(qptr + 32);

  f4v acc[4];
#pragma unroll
  for (int db = 0; db < 4; ++db) acc[db] = f4v{0.f, 0.f, 0.f, 0.f};
  float m_ = -1e30f, l_ = 0.f;

  const USH* kbase = kh + (bh << 16);
  const USH* vbase = vT + (bh << 16);
  const float* bias_b = rb + (h << 20) + (f_row << 10);
  const int* mask_b = mask + (b << 20) + (f_row << 10);

  const int c0 = tid, c1 = tid + 256;
  const int kr0 = c0 >> 3, kc0 = ((c0 & 7) ^ (kr0 & 7)) * 8;
  const int kr1 = c1 >> 3, kc1 = ((c1 & 7) ^ (kr1 & 7)) * 8;

  if constexpr (ABL == 1) {             // init LDS so reads aren't provably-uninit
    *(ushort4*)(Ks + tid * 8) = ushort4{(USH)tid, 1, 2, 3};
    *(ushort4*)(Vs + tid * 8) = ushort4{(USH)tid, 5, 6, 7};
  }

  // prologue: prefetch chunk 0 bias/mask into registers
  float4 bv4[4]; int4 mv4[4];
  if constexpr (ABL != 2) {
#pragma unroll
    for (int tb = 0; tb < 4; ++tb) {
      const int t_g = tb * 16 + lg * 4;
      bv4[tb] = *(const float4*)(bias_b + t_g);
      mv4[tb] = *(const int4*)(mask_b + t_g);
    }
  }
  float4 bn4[4]; int4 mn4[4];

  for (int tc = 0; tc < 16; ++tc) {
    const int t0 = tc * 64;
    if constexpr (ABL != 1) {
      gload16(kbase + (t0 + kr0) * 64 + kc0, Ks + c0 * 8);
      gload16(kbase + (t0 + kr1) * 64 + kc1, Ks + c1 * 8);
      gload16(vbase + kr0 * 1024 + t0 + kc0, Vs + c0 * 8);
      gload16(vbase + kr1 * 1024 + t0 + kc1, Vs + c1 * 8);
      __syncthreads();
    }
    if constexpr (ABL != 2) {
      if (tc < 15) {
#pragma unroll
        for (int tb = 0; tb < 4; ++tb) {
          const int t_g = t0 + 64 + tb * 16 + lg * 4;
          bn4[tb] = *(const float4*)(bias_b + t_g);
          mn4[tb] = *(const int4*)(mask_b + t_g);
        }
      }
    }
    // S^T = K Q^T
    f4v sa[4];
    const int sw = (l15 & 7);
    __builtin_amdgcn_s_setprio(1);
#pragma unroll
    for (int tb = 0; tb < 4; ++tb) {
      sa[tb] = f4v{0.f, 0.f, 0.f, 0.f};
      const USH* kp = Ks + (tb * 16 + l15) * 64;
      sa[tb] = MFMA16(*(const s8v*)(kp + ((lg ^ sw) * 8)), bq0, sa[tb]);
      sa[tb] = MFMA16(*(const s8v*)(kp + (((lg + 4) ^ sw) * 8)), bq1, sa[tb]);
    }
    __builtin_amdgcn_s_setprio(0);
    // scale + bias + mask
    float sv[4][4];
#pragma unroll
    for (int tb = 0; tb < 4; ++tb) {
      if constexpr (ABL != 2) {
        const float* bvp = (const float*)&bv4[tb];
        const int* mvp = (const int*)&mv4[tb];
#pragma unroll
        for (int j = 0; j < 4; ++j)
          sv[tb][j] = mvp[j] ? -10000.f : fmaf(sa[tb][j], 0.125f, bvp[j]);
      } else {
#pragma unroll
        for (int j = 0; j < 4; ++j)
          sv[tb][j] = sa[tb][j] * 0.125f;
      }
    }
    USH* Pw = Ps + w * 1152 + l15 * 72;
    if constexpr (ABL != 3) {
      // online softmax
      float mx = sv[0][0];
#pragma unroll
      for (int tb = 0; tb < 4; ++tb)
#pragma unroll
        for (int j = 0; j < 4; ++j) mx = fmaxf(mx, sv[tb][j]);
      mx = fmaxf(mx, __shfl_xor(mx, 16));
      mx = fmaxf(mx, __shfl_xor(mx, 32));
      const float mn = fmaxf(m_, mx);
      const float al = __expf(m_ - mn);
      m_ = mn;
      float rs = 0.f;
#pragma unroll
      for (int tb = 0; tb < 4; ++tb) {
        ushort4 pk;
        float p0 = __expf(sv[tb][0] - mn), p1 = __expf(sv[tb][1] - mn);
        float p2 = __expf(sv[tb][2] - mn), p3 = __expf(sv[tb][3] - mn);
        rs += (p0 + p1) + (p2 + p3);
        pk.x = f2bf(p0); pk.y = f2bf(p1); pk.z = f2bf(p2); pk.w = f2bf(p3);
        *(ushort4*)(Pw + tb * 16 + lg * 4) = pk;
      }
      rs += __shfl_xor(rs, 16);
      rs += __shfl_xor(rs, 32);
      l_ = l_ * al + rs;
      const int rbase = (lane >> 4) << 2;
      const f4v alf = {__shfl(al, rbase), __shfl(al, rbase + 1),
                       __shfl(al, rbase + 2), __shfl(al, rbase + 3)};
#pragma unroll
      for (int db = 0; db < 4; ++db) acc[db] = acc[db] * alf;
    } else {
      // NOSOFTMAX: P = sv directly (keeps QK^T+bias live, skips max/exp/shuffles)
#pragma unroll
      for (int tb = 0; tb < 4; ++tb) {
        ushort4 pk;
        pk.x = f2bf(sv[tb][0]); pk.y = f2bf(sv[tb][1]);
        pk.z = f2bf(sv[tb][2]); pk.w = f2bf(sv[tb][3]);
        *(ushort4*)(Pw + tb * 16 + lg * 4) = pk;
      }
    }
    // O += P V
    {
      const USH* Pr = Ps + w * 1152 + l15 * 72 + lg * 8;
      const s8v pa0 = *(const s8v*)Pr;
      const s8v pa1 = *(const s8v*)(Pr + 32);
      __builtin_amdgcn_s_setprio(1);
#pragma unroll
      for (int db = 0; db < 4; ++db) {
        const USH* vp = Vs + (db * 16 + l15) * 64;
        acc[db] = MFMA16(pa0, *(const s8v*)(vp + ((lg ^ sw) * 8)), acc[db]);
        acc[db] = MFMA16(pa1, *(const s8v*)(vp + (((lg + 4) ^ sw) * 8)), acc[db]);
      }
      __builtin_amdgcn_s_setprio(0);
    }
    if constexpr (ABL != 1) __syncthreads();
    if constexpr (ABL != 2) {
#pragma unroll
      for (int tb = 0; tb < 4; ++tb) { bv4[tb] = bn4[tb]; mv4[tb] = mn4[tb]; }
    }
  }
  // epilogue
  const int rbase = (lane >> 4) << 2;
  float inv[4];
#pragma unroll
  for (int j = 0; j < 4; ++j)
    inv[j] = (ABL != 3) ? 1.f / __shfl(l_, rbase + j) : 1.f;
  USH* cbase = ctx + ((size_t)((b << 10) + fb * 64 + w * 16 + lg * 4)) * 1024 + (h << 6) + l15;
#pragma unroll
  for (int db = 0; db < 4; ++db)
#pragma unroll
    for (int j = 0; j < 4; ++j)
      cbase[j * 1024 + db * 16] = f2bf(acc[db][j] * inv[j]);
}

// ---------------- launch ----------------
extern "C" void kernel_launch(void* const* d_in, const int* in_sizes, int n_in,
                              void* d_out, int out_size, void* d_ws, size_t ws_size,
                              hipStream_t stream) {
  const float* q    = (const float*)d_in[0];
  const float* k    = (const float*)d_in[1];
  const float* v    = (const float*)d_in[2];
  const int*   mask = (const int*)d_in[3];
  const float* rb   = (const float*)d_in[4];
  const float* Wq   = (const float*)d_in[5];
  const float* bq   = (const float*)d_in[6];
  const float* Wk   = (const float*)d_in[7];
  const float* bk   = (const float*)d_in[8];
  const float* Wv   = (const float*)d_in[9];
  const float* bv   = (const float*)d_in[10];
  const float* Wo   = (const float*)d_in[11];
  const float* bo   = (const float*)d_in[12];

  char* ws = (char*)d_ws;
  const size_t MB = 1024 * 1024;
  if (ws_size < 72 * MB) return;
  USH* qb    = (USH*)(ws + 0 * MB);
  USH* kb    = (USH*)(ws + 8 * MB);
  USH* vb    = (USH*)(ws + 16 * MB);
  USH* Wqb   = (USH*)(ws + 24 * MB);
  USH* Wkb   = (USH*)(ws + 26 * MB);
  USH* Wvb   = (USH*)(ws + 28 * MB);
  USH* Wob   = (USH*)(ws + 30 * MB);
  USH* qhp   = (USH*)(ws + 32 * MB);   // [B,H,F,64]
  USH* khp   = (USH*)(ws + 40 * MB);   // [B,H,T,64]
  USH* vTp   = (USH*)(ws + 48 * MB);   // [B,H,64,T]
  USH* ctxp  = (USH*)(ws + 56 * MB);   // [B,F,C]
  USH* ctxs  = (USH*)(ws + 64 * MB);   // ablation scratch output

  cvt_qkv_k<<<dim3(4096, 3), 256, 0, stream>>>(q, k, v, qb, kb, vb);
  cvt_w_k<<<dim3(1024, 4), 256, 0, stream>>>(Wq, Wk, Wv, Wo, Wqb, Wkb, Wvb, Wob);
  proj_gemm_k<<<dim3(8, 32, 3), 256, 0, stream>>>(qb, kb, vb, Wqb, Wkb, Wvb, bq, bk, bv,
                                                  qhp, khp, vTp);
  attn_abl_k<0><<<dim3(1024), 256, 0, stream>>>(qhp, khp, vTp, rb, mask, ctxp);
  out_gemm_k<<<dim3(8, 32), 256, 0, stream>>>(ctxp, Wob, bo, (float*)d_out);
  // --- ablation probes (scratch output; timing read from rocprof per-dispatch) ---
  attn_abl_k<1><<<dim3(1024), 256, 0, stream>>>(qhp, khp, vTp, rb, mask, ctxs);
  attn_abl_k<2><<<dim3(1024), 256, 0, stream>>>(qhp, khp, vTp, rb, mask, ctxs);
  attn_abl_k<3><<<dim3(1024), 256, 0, stream>>>(qhp, khp, vTp, rb, mask, ctxs);
}

// Round 10
// 179.748 us; speedup vs baseline: 1.9274x; 1.9274x over previous
//
#include <hip/hip_runtime.h>

#define USH unsigned short

using s8v = __attribute__((ext_vector_type(8))) short;   // 8 x bf16 (4 VGPR)
using f4v = __attribute__((ext_vector_type(4))) float;   // MFMA accumulator

#define MFMA16(a,b,c) __builtin_amdgcn_mfma_f32_16x16x32_bf16(a,b,c,0,0,0)

// dims: B=4, F=T=1024, C=1024, H=16, D=64

__device__ __forceinline__ USH f2bf(float f) {            // RNE f32->bf16
  unsigned int u = __builtin_bit_cast(unsigned int, f);
  u += 0x7fffu + ((u >> 16) & 1u);
  return (USH)(u >> 16);
}
__device__ __forceinline__ void gload16(const void* g, void* l) {
  __builtin_amdgcn_global_load_lds((const __attribute__((address_space(1))) void*)g,
                                   (__attribute__((address_space(3))) void*)l, 16, 0, 0);
}

// ---------------- conversion kernels ----------------
__global__ __launch_bounds__(256) void cvt_qkv_k(
    const float* __restrict__ q, const float* __restrict__ k, const float* __restrict__ v,
    USH* __restrict__ oq, USH* __restrict__ ok, USH* __restrict__ ov) {
  const int which = blockIdx.y;
  const float* in = which == 0 ? q : (which == 1 ? k : v);
  USH* out = which == 0 ? oq : (which == 1 ? ok : ov);
  const int i = blockIdx.x * 256 + threadIdx.x;           // n4 = 1<<20
  float4 val = ((const float4*)in)[i];
  ushort4 o; o.x = f2bf(val.x); o.y = f2bf(val.y); o.z = f2bf(val.z); o.w = f2bf(val.w);
  ((ushort4*)out)[i] = o;
}

__global__ __launch_bounds__(256) void cvt_w_k(
    const float* __restrict__ a, const float* __restrict__ b,
    const float* __restrict__ c, const float* __restrict__ d,
    USH* __restrict__ oa, USH* __restrict__ ob, USH* __restrict__ oc, USH* __restrict__ od) {
  const int which = blockIdx.y;
  const float* in = which == 0 ? a : which == 1 ? b : which == 2 ? c : d;
  USH* out = which == 0 ? oa : which == 1 ? ob : which == 2 ? oc : od;
  const int i = blockIdx.x * 256 + threadIdx.x;           // n4 = 262144
  float4 val = ((const float4*)in)[i];
  ushort4 o; o.x = f2bf(val.x); o.y = f2bf(val.y); o.z = f2bf(val.z); o.w = f2bf(val.w);
  ((ushort4*)out)[i] = o;
}

// ---------------- GEMM core: 128x128 tile, BK=32, K=1024, B^T layout ----------------
__device__ __forceinline__ void gemm_mainloop(
    const USH* __restrict__ A, const USH* __restrict__ W,
    int rowA0, int colW0, USH* As, USH* Bs, f4v acc[4][4], int tid) {
  const int lane = tid & 63;
  const int wid = tid >> 6;
  const int l15 = lane & 15, lg = lane >> 4;
  const int wr = (wid >> 1) * 64, wc = (wid & 1) * 64;
  for (int kk = 0; kk < 32; ++kk) {
    const int k0 = kk * 32;
    {                                                     // stage 8KB A + 8KB W
      const int c0 = tid, c1 = 256 + tid;
      gload16(A + (rowA0 + (c0 >> 2)) * 1024 + k0 + (c0 & 3) * 8, As + c0 * 8);
      gload16(A + (rowA0 + (c1 >> 2)) * 1024 + k0 + (c1 & 3) * 8, As + c1 * 8);
      gload16(W + (colW0 + (c0 >> 2)) * 1024 + k0 + (c0 & 3) * 8, Bs + c0 * 8);
      gload16(W + (colW0 + (c1 >> 2)) * 1024 + k0 + (c1 & 3) * 8, Bs + c1 * 8);
    }
    __syncthreads();
    s8v a[4], b[4];
    const USH* ap = As + (wr + l15) * 32 + lg * 8;
    const USH* bp = Bs + (wc + l15) * 32 + lg * 8;
#pragma unroll
    for (int m = 0; m < 4; ++m) a[m] = *(const s8v*)(ap + m * 512);
#pragma unroll
    for (int n = 0; n < 4; ++n) b[n] = *(const s8v*)(bp + n * 512);
#pragma unroll
    for (int m = 0; m < 4; ++m)
#pragma unroll
      for (int n = 0; n < 4; ++n)
        acc[m][n] = MFMA16(a[m], b[n], acc[m][n]);
    __syncthreads();
  }
}

// fused Q/K/V projection; z selects which. Q/K -> [B,H,S,64]; V -> [B,H,64,T] (transposed)
__global__ __launch_bounds__(256) void proj_gemm_k(
    const USH* __restrict__ qb, const USH* __restrict__ kb, const USH* __restrict__ vb,
    const USH* __restrict__ Wq, const USH* __restrict__ Wk, const USH* __restrict__ Wv,
    const float* __restrict__ bq, const float* __restrict__ bk, const float* __restrict__ bv,
    USH* __restrict__ qh, USH* __restrict__ kh, USH* __restrict__ vT) {
  __shared__ USH As[128 * 32];
  __shared__ USH Bs[128 * 32];
  const int z = blockIdx.z;
  const USH* A = z == 0 ? qb : (z == 1 ? kb : vb);
  const USH* W = z == 0 ? Wq : (z == 1 ? Wk : Wv);
  const float* bias = z == 0 ? bq : (z == 1 ? bk : bv);
  f4v acc[4][4];
#pragma unroll
  for (int m = 0; m < 4; ++m)
#pragma unroll
    for (int n = 0; n < 4; ++n) acc[m][n] = f4v{0.f, 0.f, 0.f, 0.f};
  gemm_mainloop(A, W, blockIdx.y * 128, blockIdx.x * 128, As, Bs, acc, threadIdx.x);
  const int lane = threadIdx.x & 63, wid = threadIdx.x >> 6;
  const int l15 = lane & 15, lg = lane >> 4;
  const int row0 = blockIdx.y * 128 + (wid >> 1) * 64 + lg * 4;
  const int col0 = blockIdx.x * 128 + (wid & 1) * 64 + l15;
  USH* qk_dst = (z == 0) ? qh : kh;
#pragma unroll
  for (int n = 0; n < 4; ++n) {
    const int co = col0 + n * 16;
    const float bsv = bias[co];
    const int hh = co >> 6, d = co & 63;
#pragma unroll
    for (int m = 0; m < 4; ++m)
#pragma unroll
      for (int j = 0; j < 4; ++j) {
        const int rr = row0 + m * 16 + j;
        const float v = acc[m][n][j] + bsv;
        const int bb = rr >> 10, s = rr & 1023;
        if (z < 2) qk_dst[((bb * 16 + hh) << 16) + (s << 6) + d] = f2bf(v);
        else       vT[((bb * 16 + hh) << 16) + (d << 10) + s] = f2bf(v);
      }
  }
}

// output projection: d_out = ctx @ Wo^T + bo  (f32 out)
__global__ __launch_bounds__(256) void out_gemm_k(
    const USH* __restrict__ ctx, const USH* __restrict__ Wo,
    const float* __restrict__ bo, float* __restrict__ out) {
  __shared__ USH As[128 * 32];
  __shared__ USH Bs[128 * 32];
  f4v acc[4][4];
#pragma unroll
  for (int m = 0; m < 4; ++m)
#pragma unroll
    for (int n = 0; n < 4; ++n) acc[m][n] = f4v{0.f, 0.f, 0.f, 0.f};
  gemm_mainloop(ctx, Wo, blockIdx.y * 128, blockIdx.x * 128, As, Bs, acc, threadIdx.x);
  const int lane = threadIdx.x & 63, wid = threadIdx.x >> 6;
  const int l15 = lane & 15, lg = lane >> 4;
  const int row0 = blockIdx.y * 128 + (wid >> 1) * 64 + lg * 4;
  const int col0 = blockIdx.x * 128 + (wid & 1) * 64 + l15;
#pragma unroll
  for (int n = 0; n < 4; ++n) {
    const int co = col0 + n * 16;
    const float bsv = bo[co];
#pragma unroll
    for (int m = 0; m < 4; ++m)
#pragma unroll
      for (int j = 0; j < 4; ++j) {
        const int rr = row0 + m * 16 + j;
        out[rr * 1024 + co] = acc[m][n][j] + bsv;
      }
  }
}

// ---------------- flash attention: K/V dbuf + counted vmcnt + raw s_barrier ----------------
// grid 1024 (XCD-swizzled (fb,h,b)), 256 threads = 4 waves x 16 f-rows.
// ONE raw barrier/chunk. Per iter in-flight queue: [K(tc):2, V(tc):2, bm(tc):8].
// Top-of-loop vmcnt(8) retires K/V(tc) while bm(tc) (newest 8) stays in flight
// until its compiler-managed counted wait at the softmax. No drain-all anywhere.
__global__ __launch_bounds__(256) void attn_k(
    const USH* __restrict__ qh, const USH* __restrict__ kh, const USH* __restrict__ vT,
    const float* __restrict__ rb, const int* __restrict__ mask, USH* __restrict__ ctx) {
  __shared__ USH Ks[2][64 * 64];        // [t][d], col8 XOR-swizzled by (t&7)
  __shared__ USH Vs[2][64 * 64];        // [d][t], col8 XOR-swizzled by (d&7)
  __shared__ USH Ps[4][16 * 64];        // per-wave P[f][t], col4 XOR-swizzled (no pad)
                                        // total LDS = 40960 B -> 4 blocks/CU exactly

  const int tid = threadIdx.x, lane = tid & 63, w = tid >> 6;
  const int l15 = lane & 15, lg = lane >> 4;
  const int swz = ((blockIdx.x & 7) << 7) | (blockIdx.x >> 3);
  const int fb = swz & 15, h = (swz >> 4) & 15, b = swz >> 8;
  const int bh = b * 16 + h;

  const int f_row = fb * 64 + w * 16 + l15;               // this lane's f (softmax side)
  const USH* qptr = qh + (bh << 16) + f_row * 64 + lg * 8;
  const s8v bq0 = *(const s8v*)qptr;
  const s8v bq1 = *(const s8v*)(qptr + 32);

  f4v acc[4];                                             // [db]: O[f=lg*4+j][d=db*16+l15]
#pragma unroll
  for (int db = 0; db < 4; ++db) acc[db] = f4v{0.f, 0.f, 0.f, 0.f};
  float m_ = -1e30f, l_ = 0.f;

  const USH* kbase = kh + (bh << 16);
  const USH* vbase = vT + (bh << 16);
  const float* bias_b = rb + (h << 20) + (f_row << 10);
  const int* mask_b = mask + (b << 20) + (f_row << 10);

  // staging slots (same as R3): this thread fills slots tid and tid+256
  const int c0 = tid, c1 = tid + 256;
  const int kr0 = c0 >> 3, kc0 = ((c0 & 7) ^ (kr0 & 7)) * 8;
  const int kr1 = c1 >> 3, kc1 = ((c1 & 7) ^ (kr1 & 7)) * 8;

  // ---- prologue: issue K(0),V(0) then (fenced after) bm(0) ----
  gload16(kbase + kr0 * 64 + kc0, &Ks[0][c0 * 8]);
  gload16(kbase + kr1 * 64 + kc1, &Ks[0][c1 * 8]);
  gload16(vbase + kr0 * 1024 + kc0, &Vs[0][c0 * 8]);
  gload16(vbase + kr1 * 1024 + kc1, &Vs[0][c1 * 8]);
  asm volatile("" ::: "memory");                          // K/V strictly before bm in queue
  float4 bv4[4]; int4 mv4[4];
#pragma unroll
  for (int tb = 0; tb < 4; ++tb) {
    const int t_g = tb * 16 + lg * 4;
    bv4[tb] = *(const float4*)(bias_b + t_g);
    mv4[tb] = *(const int4*)(mask_b + t_g);
  }
  float4 bn4[4]; int4 mn4[4];

  for (int tc = 0; tc < 16; ++tc) {
    const int t0 = tc * 64;
    const int cur = tc & 1;
    USH* ksc = &Ks[cur][0];
    USH* vsc = &Vs[cur][0];
    // wait K/V(tc) (all but newest 8 = bm(tc) retired), then cross-wave barrier.
    asm volatile("s_waitcnt vmcnt(8)" ::: "memory");
    __builtin_amdgcn_s_barrier();
    __builtin_amdgcn_sched_barrier(0);
    // issue next chunk: K/V(tc+1) into other buffer, then (fenced) bm(tc+1).
    if (tc < 15) {
      const int tn = t0 + 64;
      USH* ksn = &Ks[cur ^ 1][0];
      USH* vsn = &Vs[cur ^ 1][0];
      gload16(kbase + (tn + kr0) * 64 + kc0, ksn + c0 * 8);
      gload16(kbase + (tn + kr1) * 64 + kc1, ksn + c1 * 8);
      gload16(vbase + kr0 * 1024 + tn + kc0, vsn + c0 * 8);
      gload16(vbase + kr1 * 1024 + tn + kc1, vsn + c1 * 8);
      asm volatile("" ::: "memory");
#pragma unroll
      for (int tb = 0; tb < 4; ++tb) {
        const int t_g = tn + tb * 16 + lg * 4;
        bn4[tb] = *(const float4*)(bias_b + t_g);
        mn4[tb] = *(const int4*)(mask_b + t_g);
      }
    }
    // ---- compute chunk tc ----
    // S^T = K Q^T : lane holds S[t=t0+tb*16+lg*4+j][f=l15]
    f4v sa[4];
    const int sw = l15 & 7;
    __builtin_amdgcn_s_setprio(1);
#pragma unroll
    for (int tb = 0; tb < 4; ++tb) {
      sa[tb] = f4v{0.f, 0.f, 0.f, 0.f};
      const USH* kp = ksc + (tb * 16 + l15) * 64;
      sa[tb] = MFMA16(*(const s8v*)(kp + ((lg ^ sw) * 8)), bq0, sa[tb]);
      sa[tb] = MFMA16(*(const s8v*)(kp + (((lg + 4) ^ sw) * 8)), bq1, sa[tb]);
    }
    __builtin_amdgcn_s_setprio(0);
    // scale + bias + exact mask-replace (bm(tc): compiler-counted wait, still in flight)
    float sv[4][4];
#pragma unroll
    for (int tb = 0; tb < 4; ++tb) {
      const float* bvp = (const float*)&bv4[tb];
      const int* mvp = (const int*)&mv4[tb];
#pragma unroll
      for (int j = 0; j < 4; ++j)
        sv[tb][j] = mvp[j] ? -10000.f : fmaf(sa[tb][j], 0.125f, bvp[j]);
    }
    // online softmax: 16 values per lane + reduce across lg (xor 16,32)
    float mx = sv[0][0];
#pragma unroll
    for (int tb = 0; tb < 4; ++tb)
#pragma unroll
      for (int j = 0; j < 4; ++j) mx = fmaxf(mx, sv[tb][j]);
    mx = fmaxf(mx, __shfl_xor(mx, 16));
    mx = fmaxf(mx, __shfl_xor(mx, 32));
    const float mn = fmaxf(m_, mx);
    const float al = __expf(m_ - mn);
    m_ = mn;
    // P write: per-wave LDS, XOR-swizzled col4 (logical col4 L -> L ^ key2)
    const int key2 = (l15 & 7) << 1;
    USH* Pw = &Ps[w][l15 * 64];
    float rs = 0.f;
#pragma unroll
    for (int tb = 0; tb < 4; ++tb) {
      ushort4 pk;
      float p0 = __expf(sv[tb][0] - mn), p1 = __expf(sv[tb][1] - mn);
      float p2 = __expf(sv[tb][2] - mn), p3 = __expf(sv[tb][3] - mn);
      rs += (p0 + p1) + (p2 + p3);
      pk.x = f2bf(p0); pk.y = f2bf(p1); pk.z = f2bf(p2); pk.w = f2bf(p3);
      *(ushort4*)(Pw + (((tb * 4 + lg) ^ key2) << 2)) = pk;
    }
    rs += __shfl_xor(rs, 16);
    rs += __shfl_xor(rs, 32);
    l_ = l_ * al + rs;
    // broadcast al to O-fragment rows
    {
      const int rbase = (lane >> 4) << 2;
      const f4v alf = {__shfl(al, rbase), __shfl(al, rbase + 1),
                       __shfl(al, rbase + 2), __shfl(al, rbase + 3)};
#pragma unroll
      for (int db = 0; db < 4; ++db) acc[db] = acc[db] * alf;
    }
    // O += P V : A = P rows f (swizzled per-wave LDS), B = V^T rows d (swizzled Vs)
    {
      const s8v pa0 = *(const s8v*)(Pw + (((lg << 1) ^ key2) << 2));
      const s8v pa1 = *(const s8v*)(Pw + (((((lg + 4) << 1)) ^ key2) << 2));
      __builtin_amdgcn_s_setprio(1);
#pragma unroll
      for (int db = 0; db < 4; ++db) {
        const USH* vp = vsc + (db * 16 + l15) * 64;
        acc[db] = MFMA16(pa0, *(const s8v*)(vp + ((lg ^ sw) * 8)), acc[db]);
        acc[db] = MFMA16(pa1, *(const s8v*)(vp + (((lg + 4) ^ sw) * 8)), acc[db]);
      }
      __builtin_amdgcn_s_setprio(0);
    }
    // rotate prefetched bias/mask
#pragma unroll
    for (int tb = 0; tb < 4; ++tb) { bv4[tb] = bn4[tb]; mv4[tb] = mn4[tb]; }
  }
  // epilogue: ctx[b][f][h*64+d]
  const int rbase = (lane >> 4) << 2;
  float inv[4];
#pragma unroll
  for (int j = 0; j < 4; ++j) inv[j] = 1.f / __shfl(l_, rbase + j);
  USH* cbase = ctx + ((size_t)((b << 10) + fb * 64 + w * 16 + lg * 4)) * 1024 + (h << 6) + l15;
#pragma unroll
  for (int db = 0; db < 4; ++db)
#pragma unroll
    for (int j = 0; j < 4; ++j)
      cbase[j * 1024 + db * 16] = f2bf(acc[db][j] * inv[j]);
}

// ---------------- launch ----------------
extern "C" void kernel_launch(void* const* d_in, const int* in_sizes, int n_in,
                              void* d_out, int out_size, void* d_ws, size_t ws_size,
                              hipStream_t stream) {
  const float* q    = (const float*)d_in[0];
  const float* k    = (const float*)d_in[1];
  const float* v    = (const float*)d_in[2];
  const int*   mask = (const int*)d_in[3];
  const float* rb   = (const float*)d_in[4];
  const float* Wq   = (const float*)d_in[5];
  const float* bq   = (const float*)d_in[6];
  const float* Wk   = (const float*)d_in[7];
  const float* bk   = (const float*)d_in[8];
  const float* Wv   = (const float*)d_in[9];
  const float* bv   = (const float*)d_in[10];
  const float* Wo   = (const float*)d_in[11];
  const float* bo   = (const float*)d_in[12];

  char* ws = (char*)d_ws;
  const size_t MB = 1024 * 1024;
  if (ws_size < 64 * MB) return;
  USH* qb    = (USH*)(ws + 0 * MB);
  USH* kb    = (USH*)(ws + 8 * MB);
  USH* vb    = (USH*)(ws + 16 * MB);
  USH* Wqb   = (USH*)(ws + 24 * MB);
  USH* Wkb   = (USH*)(ws + 26 * MB);
  USH* Wvb   = (USH*)(ws + 28 * MB);
  USH* Wob   = (USH*)(ws + 30 * MB);
  USH* qhp   = (USH*)(ws + 32 * MB);   // [B,H,F,64]
  USH* khp   = (USH*)(ws + 40 * MB);   // [B,H,T,64]
  USH* vTp   = (USH*)(ws + 48 * MB);   // [B,H,64,T]
  USH* ctxp  = (USH*)(ws + 56 * MB);   // [B,F,C]

  cvt_qkv_k<<<dim3(4096, 3), 256, 0, stream>>>(q, k, v, qb, kb, vb);
  cvt_w_k<<<dim3(1024, 4), 256, 0, stream>>>(Wq, Wk, Wv, Wo, Wqb, Wkb, Wvb, Wob);
  proj_gemm_k<<<dim3(8, 32, 3), 256, 0, stream>>>(qb, kb, vb, Wqb, Wkb, Wvb, bq, bk, bv,
                                                  qhp, khp, vTp);
  attn_k<<<dim3(1024), 256, 0, stream>>>(qhp, khp, vTp, rb, mask, ctxp);
  out_gemm_k<<<dim3(8, 32), 256, 0, stream>>>(ctxp, Wob, bo, (float*)d_out);
}

// Round 11
// 169.006 us; speedup vs baseline: 2.0499x; 1.0636x over previous
//
#include <hip/hip_runtime.h>

#define USH unsigned short

using s8v = __attribute__((ext_vector_type(8))) short;   // 8 x bf16 (4 VGPR)
using f4v = __attribute__((ext_vector_type(4))) float;   // MFMA accumulator

#define MFMA16(a,b,c) __builtin_amdgcn_mfma_f32_16x16x32_bf16(a,b,c,0,0,0)

// dims: B=4, F=T=1024, C=1024, H=16, D=64

__device__ __forceinline__ USH f2bf(float f) {            // RNE f32->bf16
  unsigned int u = __builtin_bit_cast(unsigned int, f);
  u += 0x7fffu + ((u >> 16) & 1u);
  return (USH)(u >> 16);
}
__device__ __forceinline__ void gload16(const void* g, void* l) {
  __builtin_amdgcn_global_load_lds((const __attribute__((address_space(1))) void*)g,
                                   (__attribute__((address_space(3))) void*)l, 16, 0, 0);
}

// ---------------- conversion kernels ----------------
__global__ __launch_bounds__(256) void cvt_qkv_k(
    const float* __restrict__ q, const float* __restrict__ k, const float* __restrict__ v,
    USH* __restrict__ oq, USH* __restrict__ ok, USH* __restrict__ ov) {
  const int which = blockIdx.y;
  const float* in = which == 0 ? q : (which == 1 ? k : v);
  USH* out = which == 0 ? oq : (which == 1 ? ok : ov);
  const int i = blockIdx.x * 256 + threadIdx.x;           // n4 = 1<<20
  float4 val = ((const float4*)in)[i];
  ushort4 o; o.x = f2bf(val.x); o.y = f2bf(val.y); o.z = f2bf(val.z); o.w = f2bf(val.w);
  ((ushort4*)out)[i] = o;
}

__global__ __launch_bounds__(256) void cvt_w_k(
    const float* __restrict__ a, const float* __restrict__ b,
    const float* __restrict__ c, const float* __restrict__ d,
    USH* __restrict__ oa, USH* __restrict__ ob, USH* __restrict__ oc, USH* __restrict__ od) {
  const int which = blockIdx.y;
  const float* in = which == 0 ? a : which == 1 ? b : which == 2 ? c : d;
  USH* out = which == 0 ? oa : which == 1 ? ob : which == 2 ? oc : od;
  const int i = blockIdx.x * 256 + threadIdx.x;           // n4 = 262144
  float4 val = ((const float4*)in)[i];
  ushort4 o; o.x = f2bf(val.x); o.y = f2bf(val.y); o.z = f2bf(val.z); o.w = f2bf(val.w);
  ((ushort4*)out)[i] = o;
}

// ---------------- GEMM core: 128x128 tile, BK=32, K=1024, B^T layout ----------------
__device__ __forceinline__ void gemm_mainloop(
    const USH* __restrict__ A, const USH* __restrict__ W,
    int rowA0, int colW0, USH* As, USH* Bs, f4v acc[4][4], int tid) {
  const int lane = tid & 63;
  const int wid = tid >> 6;
  const int l15 = lane & 15, lg = lane >> 4;
  const int wr = (wid >> 1) * 64, wc = (wid & 1) * 64;
  for (int kk = 0; kk < 32; ++kk) {
    const int k0 = kk * 32;
    {                                                     // stage 8KB A + 8KB W
      const int c0 = tid, c1 = 256 + tid;
      gload16(A + (rowA0 + (c0 >> 2)) * 1024 + k0 + (c0 & 3) * 8, As + c0 * 8);
      gload16(A + (rowA0 + (c1 >> 2)) * 1024 + k0 + (c1 & 3) * 8, As + c1 * 8);
      gload16(W + (colW0 + (c0 >> 2)) * 1024 + k0 + (c0 & 3) * 8, Bs + c0 * 8);
      gload16(W + (colW0 + (c1 >> 2)) * 1024 + k0 + (c1 & 3) * 8, Bs + c1 * 8);
    }
    __syncthreads();
    s8v a[4], b[4];
    const USH* ap = As + (wr + l15) * 32 + lg * 8;
    const USH* bp = Bs + (wc + l15) * 32 + lg * 8;
#pragma unroll
    for (int m = 0; m < 4; ++m) a[m] = *(const s8v*)(ap + m * 512);
#pragma unroll
    for (int n = 0; n < 4; ++n) b[n] = *(const s8v*)(bp + n * 512);
#pragma unroll
    for (int m = 0; m < 4; ++m)
#pragma unroll
      for (int n = 0; n < 4; ++n)
        acc[m][n] = MFMA16(a[m], b[n], acc[m][n]);
    __syncthreads();
  }
}

// fused Q/K/V projection; z selects which. Q/K -> [B,H,S,64]; V -> [B,H,64,T] (transposed)
__global__ __launch_bounds__(256) void proj_gemm_k(
    const USH* __restrict__ qb, const USH* __restrict__ kb, const USH* __restrict__ vb,
    const USH* __restrict__ Wq, const USH* __restrict__ Wk, const USH* __restrict__ Wv,
    const float* __restrict__ bq, const float* __restrict__ bk, const float* __restrict__ bv,
    USH* __restrict__ qh, USH* __restrict__ kh, USH* __restrict__ vT) {
  __shared__ USH As[128 * 32];
  __shared__ USH Bs[128 * 32];
  const int z = blockIdx.z;
  const USH* A = z == 0 ? qb : (z == 1 ? kb : vb);
  const USH* W = z == 0 ? Wq : (z == 1 ? Wk : Wv);
  const float* bias = z == 0 ? bq : (z == 1 ? bk : bv);
  f4v acc[4][4];
#pragma unroll
  for (int m = 0; m < 4; ++m)
#pragma unroll
    for (int n = 0; n < 4; ++n) acc[m][n] = f4v{0.f, 0.f, 0.f, 0.f};
  gemm_mainloop(A, W, blockIdx.y * 128, blockIdx.x * 128, As, Bs, acc, threadIdx.x);
  const int lane = threadIdx.x & 63, wid = threadIdx.x >> 6;
  const int l15 = lane & 15, lg = lane >> 4;
  const int row0 = blockIdx.y * 128 + (wid >> 1) * 64 + lg * 4;
  const int col0 = blockIdx.x * 128 + (wid & 1) * 64 + l15;
  USH* qk_dst = (z == 0) ? qh : kh;
#pragma unroll
  for (int n = 0; n < 4; ++n) {
    const int co = col0 + n * 16;
    const float bsv = bias[co];
    const int hh = co >> 6, d = co & 63;
#pragma unroll
    for (int m = 0; m < 4; ++m)
#pragma unroll
      for (int j = 0; j < 4; ++j) {
        const int rr = row0 + m * 16 + j;
        const float v = acc[m][n][j] + bsv;
        const int bb = rr >> 10, s = rr & 1023;
        if (z < 2) qk_dst[((bb * 16 + hh) << 16) + (s << 6) + d] = f2bf(v);
        else       vT[((bb * 16 + hh) << 16) + (d << 10) + s] = f2bf(v);
      }
  }
}

// output projection: d_out = ctx @ Wo^T + bo  (f32 out)
__global__ __launch_bounds__(256) void out_gemm_k(
    const USH* __restrict__ ctx, const USH* __restrict__ Wo,
    const float* __restrict__ bo, float* __restrict__ out) {
  __shared__ USH As[128 * 32];
  __shared__ USH Bs[128 * 32];
  f4v acc[4][4];
#pragma unroll
  for (int m = 0; m < 4; ++m)
#pragma unroll
    for (int n = 0; n < 4; ++n) acc[m][n] = f4v{0.f, 0.f, 0.f, 0.f};
  gemm_mainloop(ctx, Wo, blockIdx.y * 128, blockIdx.x * 128, As, Bs, acc, threadIdx.x);
  const int lane = threadIdx.x & 63, wid = threadIdx.x >> 6;
  const int l15 = lane & 15, lg = lane >> 4;
  const int row0 = blockIdx.y * 128 + (wid >> 1) * 64 + lg * 4;
  const int col0 = blockIdx.x * 128 + (wid & 1) * 64 + l15;
#pragma unroll
  for (int n = 0; n < 4; ++n) {
    const int co = col0 + n * 16;
    const float bsv = bo[co];
#pragma unroll
    for (int m = 0; m < 4; ++m)
#pragma unroll
      for (int j = 0; j < 4; ++j) {
        const int rr = row0 + m * 16 + j;
        out[rr * 1024 + co] = acc[m][n][j] + bsv;
      }
  }
}

// ---------------- flash attention: R7 structure + DUAL independent softmax streams ----------------
// grid 1024 (XCD-swizzled), 256 threads = 4 waves x 16 f-rows. Per chunk each wave runs
// TWO register-independent chains (t-half A = 0..31, B = 32..63) with separate (m,l,acc),
// merged at the epilogue. Chain A's latencies (shfl/exp/LDS/MFMA) hide under chain B.
__global__ __launch_bounds__(256, 4) void attn_k(
    const USH* __restrict__ qh, const USH* __restrict__ kh, const USH* __restrict__ vT,
    const float* __restrict__ rb, const int* __restrict__ mask, USH* __restrict__ ctx) {
  __shared__ USH Ks[64 * 64];           // [t][d], col8 XOR-swizzled by (t&7)
  __shared__ USH Vs[64 * 64];           // [d][t], col8 XOR-swizzled by (d&7)
  __shared__ USH Ps[4][2][16 * 40];     // per-wave, per-stream P[f][32t], pad 40

  const int tid = threadIdx.x, lane = tid & 63, w = tid >> 6;
  const int l15 = lane & 15, lg = lane >> 4;
  const int swz = ((blockIdx.x & 7) << 7) | (blockIdx.x >> 3);
  const int fb = swz & 15, h = (swz >> 4) & 15, b = swz >> 8;
  const int bh = b * 16 + h;

  const int f_row = fb * 64 + w * 16 + l15;               // this lane's f (softmax side)
  const USH* qptr = qh + (bh << 16) + f_row * 64 + lg * 8;
  const s8v bq0 = *(const s8v*)qptr;
  const s8v bq1 = *(const s8v*)(qptr + 32);

  f4v accA[4], accB[4];                                   // [db]: O[f=lg*4+j][d=db*16+l15]
#pragma unroll
  for (int db = 0; db < 4; ++db) {
    accA[db] = f4v{0.f, 0.f, 0.f, 0.f};
    accB[db] = f4v{0.f, 0.f, 0.f, 0.f};
  }
  float mA = -1e30f, lA = 0.f;                            // stream A state (t-half 0)
  float mB = -1e30f, lB = 0.f;                            // stream B state (t-half 1)

  const USH* kbase = kh + (bh << 16);
  const USH* vbase = vT + (bh << 16);
  const float* bias_b = rb + (h << 20) + (f_row << 10);
  const int* mask_b = mask + (b << 20) + (f_row << 10);

  // staging slots: this thread fills slots tid and tid+256 of each of Ks, Vs
  const int c0 = tid, c1 = tid + 256;
  const int kr0 = c0 >> 3, kc0 = ((c0 & 7) ^ (kr0 & 7)) * 8;
  const int kr1 = c1 >> 3, kc1 = ((c1 & 7) ^ (kr1 & 7)) * 8;

  for (int tc = 0; tc < 16; ++tc) {
    const int t0 = tc * 64;
    {
      gload16(kbase + (t0 + kr0) * 64 + kc0, Ks + c0 * 8);
      gload16(kbase + (t0 + kr1) * 64 + kc1, Ks + c1 * 8);
      gload16(vbase + kr0 * 1024 + t0 + kc0, Vs + c0 * 8);
      gload16(vbase + kr1 * 1024 + t0 + kc1, Vs + c1 * 8);
    }
    __syncthreads();
    // JIT bias/mask for both streams (independent consumers; chains cover each other)
    float4 bvA[2], bvB[2]; int4 mvA[2], mvB[2];
#pragma unroll
    for (int tb = 0; tb < 2; ++tb) {
      const int tA = t0 + tb * 16 + lg * 4;
      bvA[tb] = *(const float4*)(bias_b + tA);
      mvA[tb] = *(const int4*)(mask_b + tA);
      bvB[tb] = *(const float4*)(bias_b + tA + 32);
      mvB[tb] = *(const int4*)(mask_b + tA + 32);
    }
    // S^T = K Q^T : stream A rows t-local 0..31, stream B rows 32..63
    f4v saA[2], saB[2];
    const int sw = l15 & 7;
    __builtin_amdgcn_s_setprio(1);
#pragma unroll
    for (int tb = 0; tb < 2; ++tb) {
      saA[tb] = f4v{0.f, 0.f, 0.f, 0.f};
      saB[tb] = f4v{0.f, 0.f, 0.f, 0.f};
      const USH* kpA = Ks + (tb * 16 + l15) * 64;
      const USH* kpB = Ks + ((tb + 2) * 16 + l15) * 64;
      saA[tb] = MFMA16(*(const s8v*)(kpA + ((lg ^ sw) * 8)), bq0, saA[tb]);
      saB[tb] = MFMA16(*(const s8v*)(kpB + ((lg ^ sw) * 8)), bq0, saB[tb]);
      saA[tb] = MFMA16(*(const s8v*)(kpA + (((lg + 4) ^ sw) * 8)), bq1, saA[tb]);
      saB[tb] = MFMA16(*(const s8v*)(kpB + (((lg + 4) ^ sw) * 8)), bq1, saB[tb]);
    }
    __builtin_amdgcn_s_setprio(0);
    // scale + bias + exact mask-replace (both streams)
    float svA[2][4], svB[2][4];
#pragma unroll
    for (int tb = 0; tb < 2; ++tb) {
      const float* bpA = (const float*)&bvA[tb]; const int* mpA = (const int*)&mvA[tb];
      const float* bpB = (const float*)&bvB[tb]; const int* mpB = (const int*)&mvB[tb];
#pragma unroll
      for (int j = 0; j < 4; ++j) {
        svA[tb][j] = mpA[j] ? -10000.f : fmaf(saA[tb][j], 0.125f, bpA[j]);
        svB[tb][j] = mpB[j] ? -10000.f : fmaf(saB[tb][j], 0.125f, bpB[j]);
      }
    }
    // online softmax: two independent 8-value chains + lg-reduction (xor 16,32)
    float mxA = fmaxf(fmaxf(fmaxf(svA[0][0], svA[0][1]), fmaxf(svA[0][2], svA[0][3])),
                      fmaxf(fmaxf(svA[1][0], svA[1][1]), fmaxf(svA[1][2], svA[1][3])));
    float mxB = fmaxf(fmaxf(fmaxf(svB[0][0], svB[0][1]), fmaxf(svB[0][2], svB[0][3])),
                      fmaxf(fmaxf(svB[1][0], svB[1][1]), fmaxf(svB[1][2], svB[1][3])));
    mxA = fmaxf(mxA, __shfl_xor(mxA, 16));
    mxB = fmaxf(mxB, __shfl_xor(mxB, 16));
    mxA = fmaxf(mxA, __shfl_xor(mxA, 32));
    mxB = fmaxf(mxB, __shfl_xor(mxB, 32));
    const float mnA = fmaxf(mA, mxA);
    const float mnB = fmaxf(mB, mxB);
    const float alA = __expf(mA - mnA);
    const float alB = __expf(mB - mnB);
    mA = mnA; mB = mnB;
    USH* PwA = &Ps[w][0][l15 * 40];
    USH* PwB = &Ps[w][1][l15 * 40];
    float rsA = 0.f, rsB = 0.f;
#pragma unroll
    for (int tb = 0; tb < 2; ++tb) {
      float a0 = __expf(svA[tb][0] - mnA), a1 = __expf(svA[tb][1] - mnA);
      float a2 = __expf(svA[tb][2] - mnA), a3 = __expf(svA[tb][3] - mnA);
      float b0 = __expf(svB[tb][0] - mnB), b1 = __expf(svB[tb][1] - mnB);
      float b2 = __expf(svB[tb][2] - mnB), b3 = __expf(svB[tb][3] - mnB);
      rsA += (a0 + a1) + (a2 + a3);
      rsB += (b0 + b1) + (b2 + b3);
      ushort4 pkA; pkA.x = f2bf(a0); pkA.y = f2bf(a1); pkA.z = f2bf(a2); pkA.w = f2bf(a3);
      ushort4 pkB; pkB.x = f2bf(b0); pkB.y = f2bf(b1); pkB.z = f2bf(b2); pkB.w = f2bf(b3);
      *(ushort4*)(PwA + tb * 16 + lg * 4) = pkA;
      *(ushort4*)(PwB + tb * 16 + lg * 4) = pkB;
    }
    rsA += __shfl_xor(rsA, 16);
    rsB += __shfl_xor(rsB, 16);
    rsA += __shfl_xor(rsA, 32);
    rsB += __shfl_xor(rsB, 32);
    lA = lA * alA + rsA;
    lB = lB * alB + rsB;
    // broadcast rescale factors to O-fragment rows (two independent 4-shfl sets)
    {
      const int rbase = (lane >> 4) << 2;
      const f4v alfA = {__shfl(alA, rbase), __shfl(alA, rbase + 1),
                        __shfl(alA, rbase + 2), __shfl(alA, rbase + 3)};
      const f4v alfB = {__shfl(alB, rbase), __shfl(alB, rbase + 1),
                        __shfl(alB, rbase + 2), __shfl(alB, rbase + 3)};
#pragma unroll
      for (int db = 0; db < 4; ++db) { accA[db] = accA[db] * alfA; accB[db] = accB[db] * alfB; }
    }
    // O += P V : stream A uses V t-slices 0..3 (lg), B uses 4..7 (lg+4)
    {
      const s8v paA = *(const s8v*)(PwA + lg * 8);
      const s8v paB = *(const s8v*)(PwB + lg * 8);
      __builtin_amdgcn_s_setprio(1);
#pragma unroll
      for (int db = 0; db < 4; ++db) {
        const USH* vp = Vs + (db * 16 + l15) * 64;
        accA[db] = MFMA16(paA, *(const s8v*)(vp + ((lg ^ sw) * 8)), accA[db]);
        accB[db] = MFMA16(paB, *(const s8v*)(vp + (((lg + 4) ^ sw) * 8)), accB[db]);
      }
      __builtin_amdgcn_s_setprio(0);
    }
    __syncthreads();
  }
  // epilogue: merge the two streams, then normalize and store.
  const float M = fmaxf(mA, mB);
  const float eA = __expf(mA - M), eB = __expf(mB - M);
  const float li = 1.f / (lA * eA + lB * eB);
  const float sA = eA * li, sB = eB * li;
  const int rbase = (lane >> 4) << 2;
  float sAj[4], sBj[4];
#pragma unroll
  for (int j = 0; j < 4; ++j) {
    sAj[j] = __shfl(sA, rbase + j);
    sBj[j] = __shfl(sB, rbase + j);
  }
  USH* cbase = ctx + ((size_t)((b << 10) + fb * 64 + w * 16 + lg * 4)) * 1024 + (h << 6) + l15;
#pragma unroll
  for (int db = 0; db < 4; ++db)
#pragma unroll
    for (int j = 0; j < 4; ++j)
      cbase[j * 1024 + db * 16] = f2bf(accA[db][j] * sAj[j] + accB[db][j] * sBj[j]);
}

// ---------------- launch ----------------
extern "C" void kernel_launch(void* const* d_in, const int* in_sizes, int n_in,
                              void* d_out, int out_size, void* d_ws, size_t ws_size,
                              hipStream_t stream) {
  const float* q    = (const float*)d_in[0];
  const float* k    = (const float*)d_in[1];
  const float* v    = (const float*)d_in[2];
  const int*   mask = (const int*)d_in[3];
  const float* rb   = (const float*)d_in[4];
  const float* Wq   = (const float*)d_in[5];
  const float* bq   = (const float*)d_in[6];
  const float* Wk   = (const float*)d_in[7];
  const float* bk   = (const float*)d_in[8];
  const float* Wv   = (const float*)d_in[9];
  const float* bv   = (const float*)d_in[10];
  const float* Wo   = (const float*)d_in[11];
  const float* bo   = (const float*)d_in[12];

  char* ws = (char*)d_ws;
  const size_t MB = 1024 * 1024;
  if (ws_size < 64 * MB) return;
  USH* qb    = (USH*)(ws + 0 * MB);
  USH* kb    = (USH*)(ws + 8 * MB);
  USH* vb    = (USH*)(ws + 16 * MB);
  USH* Wqb   = (USH*)(ws + 24 * MB);
  USH* Wkb   = (USH*)(ws + 26 * MB);
  USH* Wvb   = (USH*)(ws + 28 * MB);
  USH* Wob   = (USH*)(ws + 30 * MB);
  USH* qhp   = (USH*)(ws + 32 * MB);   // [B,H,F,64]
  USH* khp   = (USH*)(ws + 40 * MB);   // [B,H,T,64]
  USH* vTp   = (USH*)(ws + 48 * MB);   // [B,H,64,T]
  USH* ctxp  = (USH*)(ws + 56 * MB);   // [B,F,C]

  cvt_qkv_k<<<dim3(4096, 3), 256, 0, stream>>>(q, k, v, qb, kb, vb);
  cvt_w_k<<<dim3(1024, 4), 256, 0, stream>>>(Wq, Wk, Wv, Wo, Wqb, Wkb, Wvb, Wob);
  proj_gemm_k<<<dim3(8, 32, 3), 256, 0, stream>>>(qb, kb, vb, Wqb, Wkb, Wvb, bq, bk, bv,
                                                  qhp, khp, vTp);
  attn_k<<<dim3(1024), 256, 0, stream>>>(qhp, khp, vTp, rb, mask, ctxp);
  out_gemm_k<<<dim3(8, 32), 256, 0, stream>>>(ctxp, Wob, bo, (float*)d_out);
}

// Round 13
// 163.987 us; speedup vs baseline: 2.1127x; 1.0306x over previous
//
#include <hip/hip_runtime.h>

#define USH unsigned short

using s8v = __attribute__((ext_vector_type(8))) short;   // 8 x bf16 (4 VGPR)
using f4v = __attribute__((ext_vector_type(4))) float;   // MFMA accumulator

#define MFMA16(a,b,c) __builtin_amdgcn_mfma_f32_16x16x32_bf16(a,b,c,0,0,0)

// dims: B=4, F=T=1024, C=1024, H=16, D=64

__device__ __forceinline__ USH f2bf(float f) {            // RNE f32->bf16
  unsigned int u = __builtin_bit_cast(unsigned int, f);
  u += 0x7fffu + ((u >> 16) & 1u);
  return (USH)(u >> 16);
}
__device__ __forceinline__ void gload16(const void* g, void* l) {
  __builtin_amdgcn_global_load_lds((const __attribute__((address_space(1))) void*)g,
                                   (__attribute__((address_space(3))) void*)l, 16, 0, 0);
}

// ---------------- conversion kernels ----------------
__global__ __launch_bounds__(256) void cvt_qkv_k(
    const float* __restrict__ q, const float* __restrict__ k, const float* __restrict__ v,
    USH* __restrict__ oq, USH* __restrict__ ok, USH* __restrict__ ov) {
  const int which = blockIdx.y;
  const float* in = which == 0 ? q : (which == 1 ? k : v);
  USH* out = which == 0 ? oq : (which == 1 ? ok : ov);
  const int i = blockIdx.x * 256 + threadIdx.x;           // n4 = 1<<20
  float4 val = ((const float4*)in)[i];
  ushort4 o; o.x = f2bf(val.x); o.y = f2bf(val.y); o.z = f2bf(val.z); o.w = f2bf(val.w);
  ((ushort4*)out)[i] = o;
}

__global__ __launch_bounds__(256) void cvt_w_k(
    const float* __restrict__ a, const float* __restrict__ b,
    const float* __restrict__ c, const float* __restrict__ d,
    USH* __restrict__ oa, USH* __restrict__ ob, USH* __restrict__ oc, USH* __restrict__ od) {
  const int which = blockIdx.y;
  const float* in = which == 0 ? a : which == 1 ? b : which == 2 ? c : d;
  USH* out = which == 0 ? oa : which == 1 ? ob : which == 2 ? oc : od;
  const int i = blockIdx.x * 256 + threadIdx.x;           // n4 = 262144
  float4 val = ((const float4*)in)[i];
  ushort4 o; o.x = f2bf(val.x); o.y = f2bf(val.y); o.z = f2bf(val.z); o.w = f2bf(val.w);
  ((ushort4*)out)[i] = o;
}

// bit-pack mask: [B,F,T] int32 -> [B,F,T/32] uint32 (bit=1 means "masked")
__global__ __launch_bounds__(256) void pack_mask_k(
    const int* __restrict__ in, unsigned* __restrict__ out) {
  const int widx = blockIdx.x * 256 + threadIdx.x;        // 131072 words
  const int4* p = (const int4*)(in + widx * 32);
  unsigned m = 0;
#pragma unroll
  for (int qq = 0; qq < 8; ++qq) {
    int4 v = p[qq];
    m |= (unsigned)(v.x != 0) << (qq * 4);
    m |= (unsigned)(v.y != 0) << (qq * 4 + 1);
    m |= (unsigned)(v.z != 0) << (qq * 4 + 2);
    m |= (unsigned)(v.w != 0) << (qq * 4 + 3);
  }
  out[widx] = m;
}

// ---------------- GEMM core: 128x128 tile, BK=32, K=1024, B^T layout ----------------
__device__ __forceinline__ void gemm_mainloop(
    const USH* __restrict__ A, const USH* __restrict__ W,
    int rowA0, int colW0, USH* As, USH* Bs, f4v acc[4][4], int tid) {
  const int lane = tid & 63;
  const int wid = tid >> 6;
  const int l15 = lane & 15, lg = lane >> 4;
  const int wr = (wid >> 1) * 64, wc = (wid & 1) * 64;
  for (int kk = 0; kk < 32; ++kk) {
    const int k0 = kk * 32;
    {                                                     // stage 8KB A + 8KB W
      const int c0 = tid, c1 = 256 + tid;
      gload16(A + (rowA0 + (c0 >> 2)) * 1024 + k0 + (c0 & 3) * 8, As + c0 * 8);
      gload16(A + (rowA0 + (c1 >> 2)) * 1024 + k0 + (c1 & 3) * 8, As + c1 * 8);
      gload16(W + (colW0 + (c0 >> 2)) * 1024 + k0 + (c0 & 3) * 8, Bs + c0 * 8);
      gload16(W + (colW0 + (c1 >> 2)) * 1024 + k0 + (c1 & 3) * 8, Bs + c1 * 8);
    }
    __syncthreads();
    s8v a[4], b[4];
    const USH* ap = As + (wr + l15) * 32 + lg * 8;
    const USH* bp = Bs + (wc + l15) * 32 + lg * 8;
#pragma unroll
    for (int m = 0; m < 4; ++m) a[m] = *(const s8v*)(ap + m * 512);
#pragma unroll
    for (int n = 0; n < 4; ++n) b[n] = *(const s8v*)(bp + n * 512);
#pragma unroll
    for (int m = 0; m < 4; ++m)
#pragma unroll
      for (int n = 0; n < 4; ++n)
        acc[m][n] = MFMA16(a[m], b[n], acc[m][n]);
    __syncthreads();
  }
}

// fused Q/K/V projection; z selects which. Q/K -> [B,H,S,64]; V -> [B,H,64,T] (transposed)
__global__ __launch_bounds__(256) void proj_gemm_k(
    const USH* __restrict__ qb, const USH* __restrict__ kb, const USH* __restrict__ vb,
    const USH* __restrict__ Wq, const USH* __restrict__ Wk, const USH* __restrict__ Wv,
    const float* __restrict__ bq, const float* __restrict__ bk, const float* __restrict__ bv,
    USH* __restrict__ qh, USH* __restrict__ kh, USH* __restrict__ vT) {
  __shared__ USH As[128 * 32];
  __shared__ USH Bs[128 * 32];
  const int z = blockIdx.z;
  const USH* A = z == 0 ? qb : (z == 1 ? kb : vb);
  const USH* W = z == 0 ? Wq : (z == 1 ? Wk : Wv);
  const float* bias = z == 0 ? bq : (z == 1 ? bk : bv);
  f4v acc[4][4];
#pragma unroll
  for (int m = 0; m < 4; ++m)
#pragma unroll
    for (int n = 0; n < 4; ++n) acc[m][n] = f4v{0.f, 0.f, 0.f, 0.f};
  gemm_mainloop(A, W, blockIdx.y * 128, blockIdx.x * 128, As, Bs, acc, threadIdx.x);
  const int lane = threadIdx.x & 63, wid = threadIdx.x >> 6;
  const int l15 = lane & 15, lg = lane >> 4;
  const int row0 = blockIdx.y * 128 + (wid >> 1) * 64 + lg * 4;
  const int col0 = blockIdx.x * 128 + (wid & 1) * 64 + l15;
  USH* qk_dst = (z == 0) ? qh : kh;
#pragma unroll
  for (int n = 0; n < 4; ++n) {
    const int co = col0 + n * 16;
    const float bsv = bias[co];
    const int hh = co >> 6, d = co & 63;
#pragma unroll
    for (int m = 0; m < 4; ++m)
#pragma unroll
      for (int j = 0; j < 4; ++j) {
        const int rr = row0 + m * 16 + j;
        const float v = acc[m][n][j] + bsv;
        const int bb = rr >> 10, s = rr & 1023;
        if (z < 2) qk_dst[((bb * 16 + hh) << 16) + (s << 6) + d] = f2bf(v);
        else       vT[((bb * 16 + hh) << 16) + (d << 10) + s] = f2bf(v);
      }
  }
}

// output projection: d_out = ctx @ Wo^T + bo  (f32 out)
__global__ __launch_bounds__(256) void out_gemm_k(
    const USH* __restrict__ ctx, const USH* __restrict__ Wo,
    const float* __restrict__ bo, float* __restrict__ out) {
  __shared__ USH As[128 * 32];
  __shared__ USH Bs[128 * 32];
  f4v acc[4][4];
#pragma unroll
  for (int m = 0; m < 4; ++m)
#pragma unroll
    for (int n = 0; n < 4; ++n) acc[m][n] = f4v{0.f, 0.f, 0.f, 0.f};
  gemm_mainloop(ctx, Wo, blockIdx.y * 128, blockIdx.x * 128, As, Bs, acc, threadIdx.x);
  const int lane = threadIdx.x & 63, wid = threadIdx.x >> 6;
  const int l15 = lane & 15, lg = lane >> 4;
  const int row0 = blockIdx.y * 128 + (wid >> 1) * 64 + lg * 4;
  const int col0 = blockIdx.x * 128 + (wid & 1) * 64 + l15;
#pragma unroll
  for (int n = 0; n < 4; ++n) {
    const int co = col0 + n * 16;
    const float bsv = bo[co];
#pragma unroll
    for (int m = 0; m < 4; ++m)
#pragma unroll
      for (int j = 0; j < 4; ++j) {
        const int rr = row0 + m * 16 + j;
        out[rr * 1024 + co] = acc[m][n][j] + bsv;
      }
  }
}

// ---------------- flash attention (R7 structure; b-innermost swizzle + packed mask) ----------------
// grid 1024, 256 threads = 4 waves x 16 f-rows. Blocks sharing one (h,fb) — same bias
// slice — sit adjacent on one XCD so bias hits L2. Mask is 1 bit/element (8 B/lane/chunk).
__global__ __launch_bounds__(256) void attn_k(
    const USH* __restrict__ qh, const USH* __restrict__ kh, const USH* __restrict__ vT,
    const float* __restrict__ rb, const unsigned* __restrict__ maskp, USH* __restrict__ ctx) {
  __shared__ USH Ks[64 * 64];           // [t][d], col8 XOR-swizzled by (t&7)
  __shared__ USH Vs[64 * 64];           // [d][t], col8 XOR-swizzled by (d&7)
  __shared__ USH Ps[4 * 16 * 72];       // per-wave P[f][t], pad 72

  const int tid = threadIdx.x, lane = tid & 63, w = tid >> 6;
  const int l15 = lane & 15, lg = lane >> 4;
  // b innermost within XCD: groups of 4 adjacent blocks share (h,fb) -> bias L2 reuse
  const int swz = ((blockIdx.x & 7) << 7) | (blockIdx.x >> 3);
  const int b = swz & 3, fb = (swz >> 2) & 15, h = (swz >> 6) & 15;
  const int bh = b * 16 + h;

  const int f_row = fb * 64 + w * 16 + l15;               // this lane's f (softmax side)
  const USH* qptr = qh + (bh << 16) + f_row * 64 + lg * 8;
  const s8v bq0 = *(const s8v*)qptr;
  const s8v bq1 = *(const s8v*)(qptr + 32);

  f4v acc[4];                                             // [db]: O[f=lg*4+j][d=db*16+l15]
#pragma unroll
  for (int db = 0; db < 4; ++db) acc[db] = f4v{0.f, 0.f, 0.f, 0.f};
  float m_ = -1e30f, l_ = 0.f;

  const USH* kbase = kh + (bh << 16);
  const USH* vbase = vT + (bh << 16);
  const float* bias_b = rb + (h << 20) + (f_row << 10);
  const unsigned* mask_w = maskp + (((b << 10) + f_row) << 5);  // 32 words per row

  // staging slots: this thread fills slots tid and tid+256 of each of Ks, Vs
  const int c0 = tid, c1 = tid + 256;
  const int kr0 = c0 >> 3, kc0 = ((c0 & 7) ^ (kr0 & 7)) * 8;
  const int kr1 = c1 >> 3, kc1 = ((c1 & 7) ^ (kr1 & 7)) * 8;

  // prologue: prefetch chunk 0 bias + packed mask into registers
  float4 bv4[4]; uint2 mw;
#pragma unroll
  for (int tb = 0; tb < 4; ++tb)
    bv4[tb] = *(const float4*)(bias_b + tb * 16 + lg * 4);
  mw = *(const uint2*)(mask_w);
  float4 bn4[4]; uint2 mwn;

  for (int tc = 0; tc < 16; ++tc) {
    const int t0 = tc * 64;
    {
      gload16(kbase + (t0 + kr0) * 64 + kc0, Ks + c0 * 8);
      gload16(kbase + (t0 + kr1) * 64 + kc1, Ks + c1 * 8);
      gload16(vbase + kr0 * 1024 + t0 + kc0, Vs + c0 * 8);
      gload16(vbase + kr1 * 1024 + t0 + kc1, Vs + c1 * 8);
    }
    __syncthreads();
    // issue NEXT chunk's bias/mask loads right after the barrier
    if (tc < 15) {
      const int tn = t0 + 64;
#pragma unroll
      for (int tb = 0; tb < 4; ++tb)
        bn4[tb] = *(const float4*)(bias_b + tn + tb * 16 + lg * 4);
      mwn = *(const uint2*)(mask_w + (tn >> 5));
    }
    // S^T = K Q^T : lane holds S[t=t0+tb*16+lg*4+j][f=l15]
    f4v sa[4];
    const int sw = (l15 & 7);
    __builtin_amdgcn_s_setprio(1);
#pragma unroll
    for (int tb = 0; tb < 4; ++tb) {
      sa[tb] = f4v{0.f, 0.f, 0.f, 0.f};
      const USH* kp = Ks + (tb * 16 + l15) * 64;
      sa[tb] = MFMA16(*(const s8v*)(kp + ((lg ^ sw) * 8)), bq0, sa[tb]);
      sa[tb] = MFMA16(*(const s8v*)(kp + (((lg + 4) ^ sw) * 8)), bq1, sa[tb]);
    }
    __builtin_amdgcn_s_setprio(0);
    // scale + bias + exact mask-replace (mask bit k = tb*16+lg*4+j of the 64-bit pair)
    const unsigned u0 = mw.x >> (lg * 4);
    const unsigned u1 = mw.y >> (lg * 4);
    float sv[4][4];
#pragma unroll
    for (int tb = 0; tb < 4; ++tb) {
      const float* bvp = (const float*)&bv4[tb];
      const unsigned uu = (tb < 2) ? u0 : u1;
      const int sh = (tb & 1) * 16;
#pragma unroll
      for (int j = 0; j < 4; ++j)
        sv[tb][j] = ((uu >> (sh + j)) & 1u) ? -10000.f : fmaf(sa[tb][j], 0.125f, bvp[j]);
    }
    // online softmax: 16 values per lane + reduce across lg (xor 16,32)
    float mx = sv[0][0];
#pragma unroll
    for (int tb = 0; tb < 4; ++tb)
#pragma unroll
      for (int j = 0; j < 4; ++j) mx = fmaxf(mx, sv[tb][j]);
    mx = fmaxf(mx, __shfl_xor(mx, 16));
    mx = fmaxf(mx, __shfl_xor(mx, 32));
    const float mn = fmaxf(m_, mx);
    const float al = __expf(m_ - mn);
    m_ = mn;
    float rs = 0.f;
    USH* Pw = Ps + w * 1152 + l15 * 72;
#pragma unroll
    for (int tb = 0; tb < 4; ++tb) {
      ushort4 pk;
      float p0 = __expf(sv[tb][0] - mn), p1 = __expf(sv[tb][1] - mn);
      float p2 = __expf(sv[tb][2] - mn), p3 = __expf(sv[tb][3] - mn);
      rs += (p0 + p1) + (p2 + p3);
      pk.x = f2bf(p0); pk.y = f2bf(p1); pk.z = f2bf(p2); pk.w = f2bf(p3);
      *(ushort4*)(Pw + tb * 16 + lg * 4) = pk;
    }
    rs += __shfl_xor(rs, 16);
    rs += __shfl_xor(rs, 32);
    l_ = l_ * al + rs;
    // broadcast al to O-fragment rows (row f-local = lg*4+j lives at src lane lg*4+j)
    {
      const int rbase = (lane >> 4) << 2;
      const f4v alf = {__shfl(al, rbase), __shfl(al, rbase + 1),
                       __shfl(al, rbase + 2), __shfl(al, rbase + 3)};
#pragma unroll
      for (int db = 0; db < 4; ++db) acc[db] = acc[db] * alf;
    }
    // O += P V : A = P rows f (per-wave LDS), B = V^T rows d (swizzled Vs)
    {
      const USH* Pr = Ps + w * 1152 + l15 * 72 + lg * 8;
      const s8v pa0 = *(const s8v*)Pr;
      const s8v pa1 = *(const s8v*)(Pr + 32);
      __builtin_amdgcn_s_setprio(1);
#pragma unroll
      for (int db = 0; db < 4; ++db) {
        const USH* vp = Vs + (db * 16 + l15) * 64;
        acc[db] = MFMA16(pa0, *(const s8v*)(vp + ((lg ^ sw) * 8)), acc[db]);
        acc[db] = MFMA16(pa1, *(const s8v*)(vp + (((lg + 4) ^ sw) * 8)), acc[db]);
      }
      __builtin_amdgcn_s_setprio(0);
    }
    __syncthreads();
    // rotate the prefetched registers into place for the next chunk
#pragma unroll
    for (int tb = 0; tb < 4; ++tb) bv4[tb] = bn4[tb];
    mw = mwn;
  }
  // epilogue: ctx[b][f][h*64+d]; row f-local = lg*4+j needs l_ from lane lg*4+j
  const int rbase = (lane >> 4) << 2;
  float inv[4];
#pragma unroll
  for (int j = 0; j < 4; ++j) inv[j] = 1.f / __shfl(l_, rbase + j);
  USH* cbase = ctx + ((size_t)((b << 10) + fb * 64 + w * 16 + lg * 4)) * 1024 + (h << 6) + l15;
#pragma unroll
  for (int db = 0; db < 4; ++db)
#pragma unroll
    for (int j = 0; j < 4; ++j)
      cbase[j * 1024 + db * 16] = f2bf(acc[db][j] * inv[j]);
}

// ---------------- launch ----------------
extern "C" void kernel_launch(void* const* d_in, const int* in_sizes, int n_in,
                              void* d_out, int out_size, void* d_ws, size_t ws_size,
                              hipStream_t stream) {
  const float* q    = (const float*)d_in[0];
  const float* k    = (const float*)d_in[1];
  const float* v    = (const float*)d_in[2];
  const int*   mask = (const int*)d_in[3];
  const float* rb   = (const float*)d_in[4];
  const float* Wq   = (const float*)d_in[5];
  const float* bq   = (const float*)d_in[6];
  const float* Wk   = (const float*)d_in[7];
  const float* bk   = (const float*)d_in[8];
  const float* Wv   = (const float*)d_in[9];
  const float* bv   = (const float*)d_in[10];
  const float* Wo   = (const float*)d_in[11];
  const float* bo   = (const float*)d_in[12];

  char* ws = (char*)d_ws;
  const size_t MB = 1024 * 1024;
  if (ws_size < 65 * MB) return;
  USH* qb    = (USH*)(ws + 0 * MB);
  USH* kb    = (USH*)(ws + 8 * MB);
  USH* vb    = (USH*)(ws + 16 * MB);
  USH* Wqb   = (USH*)(ws + 24 * MB);
  USH* Wkb   = (USH*)(ws + 26 * MB);
  USH* Wvb   = (USH*)(ws + 28 * MB);
  USH* Wob   = (USH*)(ws + 30 * MB);   // [30,32) — 2 MB, do NOT overlap!
  USH* qhp   = (USH*)(ws + 32 * MB);   // [B,H,F,64]
  USH* khp   = (USH*)(ws + 40 * MB);   // [B,H,T,64]
  USH* vTp   = (USH*)(ws + 48 * MB);   // [B,H,64,T]
  USH* ctxp  = (USH*)(ws + 56 * MB);   // [B,F,C] — [56,64)
  unsigned* maskp = (unsigned*)(ws + 64 * MB); // [B,F,32] packed (512 KB), AFTER ctxp

  cvt_qkv_k<<<dim3(4096, 3), 256, 0, stream>>>(q, k, v, qb, kb, vb);
  cvt_w_k<<<dim3(1024, 4), 256, 0, stream>>>(Wq, Wk, Wv, Wo, Wqb, Wkb, Wvb, Wob);
  pack_mask_k<<<dim3(512), 256, 0, stream>>>(mask, maskp);
  proj_gemm_k<<<dim3(8, 32, 3), 256, 0, stream>>>(qb, kb, vb, Wqb, Wkb, Wvb, bq, bk, bv,
                                                  qhp, khp, vTp);
  attn_k<<<dim3(1024), 256, 0, stream>>>(qhp, khp, vTp, rb, maskp, ctxp);
  out_gemm_k<<<dim3(8, 32), 256, 0, stream>>>(ctxp, Wob, bo, (float*)d_out);
}